// Round 3
// baseline (3574.103 us; speedup 1.0000x reference)
//
#include <hip/hip_runtime.h>

#define BA 128
#define H 256
#define TH 768

typedef _Float16 h2_t __attribute__((ext_vector_type(2)));
typedef short s8_t __attribute__((ext_vector_type(8)));
typedef float f4_t __attribute__((ext_vector_type(4)));
typedef unsigned short u16;
typedef unsigned int u32;

__device__ __forceinline__ float bf2f(u16 u) {
  union { u32 i; float f; } c; c.i = ((u32)u) << 16; return c.f;
}
__device__ __forceinline__ u16 f2bf(float f) {
  union { float f; u32 i; } c; c.f = f;
  u32 r = c.i + 0x7FFFu + ((c.i >> 16) & 1u);
  return (u16)(r >> 16);
}
__device__ __forceinline__ float sigm(float x) {
  float e = __builtin_amdgcn_exp2f(-x * 1.442695040888963f);
  return __builtin_amdgcn_rcpf(1.0f + e);
}
__device__ __forceinline__ float tanh_(float x) {
  float e = __builtin_amdgcn_exp2f(x * 2.885390081777927f);
  return 1.0f - 2.0f * __builtin_amdgcn_rcpf(1.0f + e);
}
__device__ __forceinline__ float ldf(const void* p, bool f32, size_t idx) {
  return f32 ? ((const float*)p)[idx] : bf2f(((const u16*)p)[idx]);
}
__device__ __forceinline__ int ldrst(const void* p, bool isbyte, size_t idx) {
  return isbyte ? (int)((const unsigned char*)p)[idx] : ((const int*)p)[idx];
}

// flags[0]=ins_is_f32, flags[1]=resets_is_byte, flags[2]=weights_is_f32
__global__ __launch_bounds__(256) void kdetect(const u32* __restrict__ insw,
                                               const u32* __restrict__ rstw,
                                               const u32* __restrict__ whrw,
                                               int* __restrict__ flags) {
  __shared__ int c0, c1, c2;
  if (threadIdx.x == 0) { c0 = 0; c1 = 0; c2 = 0; }
  __syncthreads();
  float a = fabsf(bf2f((u16)(insw[threadIdx.x] & 0xFFFFu)));
  if (!(a < 1e10f)) atomicAdd(&c0, 1);
  float b = fabsf(bf2f((u16)(whrw[threadIdx.x] & 0xFFFFu)));
  if (!(b < 1e10f)) atomicAdd(&c2, 1);
  if (threadIdx.x < 128 && rstw[threadIdx.x] > 1u) atomicAdd(&c1, 1);
  __syncthreads();
  if (threadIdx.x == 0) {
    flags[0] = (c0 > 8) ? 1 : 0;
    flags[1] = (c1 > 0) ? 1 : 0;
    flags[2] = (c2 > 8) ? 1 : 0;
  }
}

// convert ins -> bf16 (or pass-through copy if already bf16)
__global__ __launch_bounds__(256) void kprep(const void* __restrict__ ins,
                                             u16* __restrict__ insb,
                                             const int* __restrict__ flags) {
  bool f32in = flags[0] != 0;
  size_t i0 = ((size_t)blockIdx.x * 256 + threadIdx.x) * 8;
  s8_t v;
  if (f32in) {
    f4_t x0 = *(const f4_t*)((const float*)ins + i0);
    f4_t x1 = *(const f4_t*)((const float*)ins + i0 + 4);
#pragma unroll
    for (int i = 0; i < 4; ++i) v[i] = (short)f2bf(x0[i]);
#pragma unroll
    for (int i = 0; i < 4; ++i) v[4 + i] = (short)f2bf(x1[i]);
  } else {
    v = *(const s8_t*)((const u16*)ins + i0);
  }
  *(s8_t*)(insb + i0) = v;
}

// WT[g][j][k] = W_g[k][j], bf16
__global__ __launch_bounds__(256) void ktrans(const void* __restrict__ Wr,
                                              const void* __restrict__ Wz,
                                              const void* __restrict__ Wn,
                                              u16* __restrict__ WT,
                                              const int* __restrict__ flags) {
  __shared__ u16 tile[64][65];
  bool f32in = flags[2] != 0;
  const void* src = blockIdx.z == 0 ? Wr : (blockIdx.z == 1 ? Wz : Wn);
  int k0 = blockIdx.x * 64, j0 = blockIdx.y * 64;
  int tid = threadIdx.x;
#pragma unroll
  for (int p = 0; p < 16; ++p) {
    int e = p * 256 + tid;
    int kr = e >> 6, jc = e & 63;
    size_t idx = (size_t)(k0 + kr) * H + j0 + jc;
    tile[kr][jc] = f32in ? f2bf(((const float*)src)[idx]) : ((const u16*)src)[idx];
  }
  __syncthreads();
  u16* dst = WT + (size_t)blockIdx.z * H * H;
#pragma unroll
  for (int p = 0; p < 16; ++p) {
    int e = p * 256 + tid;
    int jr = e >> 6, kc = e & 63;
    dst[(size_t)(j0 + jr) * H + k0 + kc] = tile[kc][jr];
  }
}

// xproj[m, g*256+j] = ins[m,:] @ W_ig[:,j]  -> bf16
#define LDK 40
__global__ __launch_bounds__(256) void kgemm(const void* __restrict__ ins,
                                             const u16* __restrict__ insb, int use_insb,
                                             int t0, const u16* __restrict__ WT,
                                             u16* __restrict__ C,
                                             const int* __restrict__ flags) {
  __shared__ u16 As[128 * LDK];
  __shared__ u16 Bs[128 * LDK];
  bool f32in = flags[0] != 0;
  int tid = threadIdx.x;
  int row0 = blockIdx.x * 128;
  int col0 = blockIdx.y * 128;
  int gate = col0 >> 8;
  int j0 = col0 & 255;
  const u16* Bg = WT + (size_t)gate * H * H + (size_t)j0 * H;
  size_t abase = (size_t)t0 * BA * H;
  int lane = tid & 63;
  int wave = tid >> 6;
  int r16 = lane & 15;
  int kg = lane >> 4;
  f4_t acc[2][8];
#pragma unroll
  for (int rt = 0; rt < 2; ++rt)
#pragma unroll
    for (int ct = 0; ct < 8; ++ct) acc[rt][ct] = (f4_t)0.0f;

  for (int kk = 0; kk < 8; ++kk) {
    int k0 = kk * 32;
#pragma unroll
    for (int p = 0; p < 2; ++p) {  // A tile 128x32
      int idx = p * 256 + tid;
      int m = idx >> 2;
      int kq = (idx & 3) * 8;
      size_t e = abase + (size_t)(row0 + m) * H + k0 + kq;
      s8_t v;
      if (use_insb) {
        v = *(const s8_t*)(insb + e);
      } else if (f32in) {
        f4_t x0 = *(const f4_t*)((const float*)ins + e);
        f4_t x1 = *(const f4_t*)((const float*)ins + e + 4);
#pragma unroll
        for (int i = 0; i < 4; ++i) v[i] = (short)f2bf(x0[i]);
#pragma unroll
        for (int i = 0; i < 4; ++i) v[4 + i] = (short)f2bf(x1[i]);
      } else {
        v = *(const s8_t*)((const u16*)ins + e);
      }
      *(s8_t*)(As + m * LDK + kq) = v;
    }
#pragma unroll
    for (int p = 0; p < 2; ++p) {  // B tile
      int idx = p * 256 + tid;
      int n = idx >> 2;
      int kq = (idx & 3) * 8;
      s8_t v = *(const s8_t*)(Bg + (size_t)n * H + k0 + kq);
      *(s8_t*)(Bs + n * LDK + kq) = v;
    }
    __syncthreads();
    s8_t af[2], bf[8];
#pragma unroll
    for (int rt = 0; rt < 2; ++rt)
      af[rt] = *(const s8_t*)(As + (wave * 32 + rt * 16 + r16) * LDK + kg * 8);
#pragma unroll
    for (int ct = 0; ct < 8; ++ct)
      bf[ct] = *(const s8_t*)(Bs + (ct * 16 + r16) * LDK + kg * 8);
#pragma unroll
    for (int rt = 0; rt < 2; ++rt)
#pragma unroll
      for (int ct = 0; ct < 8; ++ct)
        acc[rt][ct] = __builtin_amdgcn_mfma_f32_16x16x32_bf16(af[rt], bf[ct], acc[rt][ct], 0, 0, 0);
    __syncthreads();
  }
  // C/D: col=lane&15, row=(lane>>4)*4+reg
#pragma unroll
  for (int rt = 0; rt < 2; ++rt)
#pragma unroll
    for (int ct = 0; ct < 8; ++ct)
#pragma unroll
      for (int r = 0; r < 4; ++r) {
        int grow = row0 + wave * 32 + rt * 16 + kg * 4 + r;
        int gcol = col0 + ct * 16 + r16;
        C[(size_t)grow * TH + gcol] = f2bf(acc[rt][ct][r]);
      }
}

// GRU scan: one WG per (b,a) sequence; f32 output
__global__ __launch_bounds__(256, 1) void kscan(
    const u16* __restrict__ xproj, const void* __restrict__ resets,
    const void* __restrict__ h0, float* __restrict__ carry,
    const void* __restrict__ Whr, const void* __restrict__ Whz, const void* __restrict__ Whn,
    const void* __restrict__ bir, const void* __restrict__ biz, const void* __restrict__ bin_,
    const void* __restrict__ bhn, float* __restrict__ out, int t0, int Tc,
    const int* __restrict__ flags) {
  int w = blockIdx.x;
  int j = threadIdx.x;
  bool wf32 = flags[2] != 0;
  bool rbyte = flags[1] != 0;
  __shared__ __align__(16) u32 hs[128];

  h2_t wr[128], wz[128], wn[128];
#pragma unroll
  for (int m = 0; m < 128; ++m) {
    wr[m] = h2_t{(_Float16)ldf(Whr, wf32, (size_t)(2 * m) * H + j),
                 (_Float16)ldf(Whr, wf32, (size_t)(2 * m + 1) * H + j)};
    wz[m] = h2_t{(_Float16)ldf(Whz, wf32, (size_t)(2 * m) * H + j),
                 (_Float16)ldf(Whz, wf32, (size_t)(2 * m + 1) * H + j)};
    wn[m] = h2_t{(_Float16)ldf(Whn, wf32, (size_t)(2 * m) * H + j),
                 (_Float16)ldf(Whn, wf32, (size_t)(2 * m + 1) * H + j)};
  }
  float vbir = ldf(bir, wf32, j), vbiz = ldf(biz, wf32, j);
  float vbin = ldf(bin_, wf32, j), vbhn = ldf(bhn, wf32, j);

  float hreg = (t0 == 0) ? ldf(h0, wf32, (size_t)w * H + j) : carry[(size_t)w * H + j];
  if (ldrst(resets, rbyte, (size_t)t0 * BA + w) != 0) hreg = 0.0f;
  ((_Float16*)hs)[j] = (_Float16)hreg;
  __syncthreads();

#pragma unroll 1
  for (int tl = 0; tl < Tc; ++tl) {
    size_t xbase = ((size_t)tl * BA + w) * TH;
    float xr = bf2f(xproj[xbase + j]);
    float xz = bf2f(xproj[xbase + H + j]);
    float xn = bf2f(xproj[xbase + 2 * H + j]);

    float ar = 0.0f, az = 0.0f, an = 0.0f;
    const uint4* h4 = (const uint4*)hs;
#pragma unroll
    for (int q = 0; q < 32; ++q) {
      uint4 hv = h4[q];
      h2_t p0 = __builtin_bit_cast(h2_t, hv.x);
      h2_t p1 = __builtin_bit_cast(h2_t, hv.y);
      h2_t p2 = __builtin_bit_cast(h2_t, hv.z);
      h2_t p3 = __builtin_bit_cast(h2_t, hv.w);
#if defined(__has_builtin) && __has_builtin(__builtin_amdgcn_fdot2)
      ar = __builtin_amdgcn_fdot2(wr[4 * q + 0], p0, ar, false);
      az = __builtin_amdgcn_fdot2(wz[4 * q + 0], p0, az, false);
      an = __builtin_amdgcn_fdot2(wn[4 * q + 0], p0, an, false);
      ar = __builtin_amdgcn_fdot2(wr[4 * q + 1], p1, ar, false);
      az = __builtin_amdgcn_fdot2(wz[4 * q + 1], p1, az, false);
      an = __builtin_amdgcn_fdot2(wn[4 * q + 1], p1, an, false);
      ar = __builtin_amdgcn_fdot2(wr[4 * q + 2], p2, ar, false);
      az = __builtin_amdgcn_fdot2(wz[4 * q + 2], p2, az, false);
      an = __builtin_amdgcn_fdot2(wn[4 * q + 2], p2, an, false);
      ar = __builtin_amdgcn_fdot2(wr[4 * q + 3], p3, ar, false);
      az = __builtin_amdgcn_fdot2(wz[4 * q + 3], p3, az, false);
      an = __builtin_amdgcn_fdot2(wn[4 * q + 3], p3, an, false);
#else
      h2_t hp[4] = {p0, p1, p2, p3};
#pragma unroll
      for (int i = 0; i < 4; ++i) {
        ar += (float)wr[4 * q + i][0] * (float)hp[i][0] + (float)wr[4 * q + i][1] * (float)hp[i][1];
        az += (float)wz[4 * q + i][0] * (float)hp[i][0] + (float)wz[4 * q + i][1] * (float)hp[i][1];
        an += (float)wn[4 * q + i][0] * (float)hp[i][0] + (float)wn[4 * q + i][1] * (float)hp[i][1];
      }
#endif
    }
    float r = sigm(xr + vbir + ar);
    float z = sigm(xz + vbiz + az);
    float n = tanh_(xn + vbin + r * (an + vbhn));
    float hnew = (1.0f - z) * n + z * hreg;
    int t = t0 + tl;
    out[((size_t)t * BA + w) * H + j] = hnew;  // f32 output

    float hnext = hnew;
    if (tl + 1 < Tc && ldrst(resets, rbyte, (size_t)(t + 1) * BA + w) != 0) hnext = 0.0f;
    __syncthreads();
    ((_Float16*)hs)[j] = (_Float16)hnext;
    hreg = hnext;
    __syncthreads();
  }
  carry[(size_t)w * H + j] = hreg;
}

extern "C" void kernel_launch(void* const* d_in, const int* in_sizes, int n_in,
                              void* d_out, int out_size, void* d_ws, size_t ws_size,
                              hipStream_t stream) {
  const void* ins = d_in[0];
  const void* resets = d_in[1];
  const void* h0 = d_in[2];
  const void* Wir = d_in[3];
  const void* Wiz = d_in[4];
  const void* Win = d_in[5];
  const void* bir = d_in[6];
  const void* biz = d_in[7];
  const void* bin_ = d_in[8];
  const void* Whr = d_in[9];
  const void* Whz = d_in[10];
  const void* Whn = d_in[11];
  const void* bhn = d_in[12];
  float* out = (float*)d_out;

  // ws: [flags 256B][WT 384KB][carry 128KB][insb 64MB?][xproj Tc*192KB bf16]
  const size_t off_wt = 256;
  const size_t off_carry = off_wt + (size_t)3 * H * H * 2;           // 393472
  const size_t off_insb = off_carry + (size_t)BA * H * 4;            // 524544
  const size_t insb_bytes = (size_t)1024 * BA * H * 2;               // 67108864
  const size_t chunk_bytes = (size_t)BA * TH * 2;                    // 196608 per t
  int use_insb = (ws_size >= off_insb + insb_bytes + chunk_bytes) ? 1 : 0;
  size_t off_xproj = use_insb ? (off_insb + insb_bytes) : off_insb;

  int Tc = 1024;
  while (Tc > 1 && off_xproj + (size_t)Tc * chunk_bytes > ws_size) Tc >>= 1;

  int* flags = (int*)d_ws;
  u16* WT = (u16*)((char*)d_ws + off_wt);
  float* carry = (float*)((char*)d_ws + off_carry);
  u16* insb = (u16*)((char*)d_ws + off_insb);
  u16* xproj = (u16*)((char*)d_ws + off_xproj);

  kdetect<<<1, 256, 0, stream>>>((const u32*)ins, (const u32*)resets, (const u32*)Whr, flags);
  if (use_insb) kprep<<<16384, 256, 0, stream>>>(ins, insb, flags);
  ktrans<<<dim3(4, 4, 3), 256, 0, stream>>>(Wir, Wiz, Win, WT, flags);
  int nchunks = 1024 / Tc;
  for (int c = 0; c < nchunks; ++c) {
    int t0 = c * Tc;
    kgemm<<<dim3(Tc, 6), 256, 0, stream>>>(ins, insb, use_insb, t0, WT, xproj, flags);
    kscan<<<128, 256, 0, stream>>>(xproj, resets, h0, carry, Whr, Whz, Whn,
                                   bir, biz, bin_, bhn, out, t0, Tc, flags);
  }
}

// Round 4
// 2877.499 us; speedup vs baseline: 1.2421x; 1.2421x over previous
//
#include <hip/hip_runtime.h>

#define BA 128
#define H 256
#define TH 768

typedef _Float16 h2_t __attribute__((ext_vector_type(2)));
typedef short s8_t __attribute__((ext_vector_type(8)));
typedef float f4_t __attribute__((ext_vector_type(4)));
typedef unsigned short u16;
typedef unsigned int u32;
typedef u32 v128u __attribute__((ext_vector_type(128)));

__device__ __forceinline__ float bf2f(u16 u) {
  union { u32 i; float f; } c; c.i = ((u32)u) << 16; return c.f;
}
__device__ __forceinline__ u16 f2bf(float f) {
  union { float f; u32 i; } c; c.f = f;
  u32 r = c.i + 0x7FFFu + ((c.i >> 16) & 1u);
  return (u16)(r >> 16);
}
__device__ __forceinline__ float sigm(float x) {
  float e = __builtin_amdgcn_exp2f(-x * 1.442695040888963f);
  return __builtin_amdgcn_rcpf(1.0f + e);
}
__device__ __forceinline__ float tanh_(float x) {
  float e = __builtin_amdgcn_exp2f(x * 2.885390081777927f);
  return 1.0f - 2.0f * __builtin_amdgcn_rcpf(1.0f + e);
}
__device__ __forceinline__ float ldf(const void* p, bool f32, size_t idx) {
  return f32 ? ((const float*)p)[idx] : bf2f(((const u16*)p)[idx]);
}
__device__ __forceinline__ int ldrst(const void* p, bool isbyte, size_t idx) {
  return isbyte ? (int)((const unsigned char*)p)[idx] : ((const int*)p)[idx];
}
__device__ __forceinline__ float F2(h2_t a, h2_t b, float c) {
#if defined(__has_builtin) && __has_builtin(__builtin_amdgcn_fdot2)
  return __builtin_amdgcn_fdot2(a, b, c, false);
#else
  return c + (float)a[0] * (float)b[0] + (float)a[1] * (float)b[1];
#endif
}
__device__ __forceinline__ u32 pk(short a, short b) {
  h2_t h{(_Float16)bf2f((u16)a), (_Float16)bf2f((u16)b)};
  return __builtin_bit_cast(u32, h);
}

// flags: [0]=ins_f32 [1]=resets_byte [2]=Wh_f32 [3]=Wi_f32
__global__ __launch_bounds__(256) void kdetect(const u32* __restrict__ insw,
                                               const u32* __restrict__ rstw,
                                               const u32* __restrict__ whrw,
                                               const u32* __restrict__ wirw,
                                               int* __restrict__ flags) {
  __shared__ int c0, c1, c2, c3;
  if (threadIdx.x == 0) { c0 = 0; c1 = 0; c2 = 0; c3 = 0; }
  __syncthreads();
  if (!(fabsf(bf2f((u16)(insw[threadIdx.x] & 0xFFFFu))) < 1e10f)) atomicAdd(&c0, 1);
  if (!(fabsf(bf2f((u16)(whrw[threadIdx.x] & 0xFFFFu))) < 1e10f)) atomicAdd(&c2, 1);
  if (!(fabsf(bf2f((u16)(wirw[threadIdx.x] & 0xFFFFu))) < 1e10f)) atomicAdd(&c3, 1);
  if (threadIdx.x < 128 && rstw[threadIdx.x] > 1u) atomicAdd(&c1, 1);
  __syncthreads();
  if (threadIdx.x == 0) {
    flags[0] = (c0 > 8) ? 1 : 0;
    flags[1] = (c1 > 0) ? 1 : 0;
    flags[2] = (c2 > 8) ? 1 : 0;
    flags[3] = (c3 > 8) ? 1 : 0;
  }
}

// convert ins -> bf16 (or pass-through)
__global__ __launch_bounds__(256) void kprep(const void* __restrict__ ins,
                                             u16* __restrict__ insb,
                                             const int* __restrict__ flags) {
  bool f32in = flags[0] != 0;
  size_t i0 = ((size_t)blockIdx.x * 256 + threadIdx.x) * 8;
  s8_t v;
  if (f32in) {
    f4_t x0 = *(const f4_t*)((const float*)ins + i0);
    f4_t x1 = *(const f4_t*)((const float*)ins + i0 + 4);
#pragma unroll
    for (int i = 0; i < 4; ++i) v[i] = (short)f2bf(x0[i]);
#pragma unroll
    for (int i = 0; i < 4; ++i) v[4 + i] = (short)f2bf(x1[i]);
  } else {
    v = *(const s8_t*)((const u16*)ins + i0);
  }
  *(s8_t*)(insb + i0) = v;
}

// WT[g][j][k] = W_g[k][j], bf16; g=0..2: Wi{r,z,n}, g=3..5: Wh{r,z,n}
__global__ __launch_bounds__(256) void ktrans(const void* __restrict__ W0, const void* __restrict__ W1,
                                              const void* __restrict__ W2, const void* __restrict__ W3,
                                              const void* __restrict__ W4, const void* __restrict__ W5,
                                              u16* __restrict__ WT, const int* __restrict__ flags) {
  __shared__ u16 tile[64][65];
  int g = blockIdx.z;
  bool f32in = ((g < 3) ? flags[3] : flags[2]) != 0;
  const void* srcs[6] = {W0, W1, W2, W3, W4, W5};
  const void* src = srcs[g];
  int k0 = blockIdx.x * 64, j0 = blockIdx.y * 64;
  int tid = threadIdx.x;
#pragma unroll
  for (int p = 0; p < 16; ++p) {
    int e = p * 256 + tid;
    int kr = e >> 6, jc = e & 63;
    size_t idx = (size_t)(k0 + kr) * H + j0 + jc;
    tile[kr][jc] = f32in ? f2bf(((const float*)src)[idx]) : ((const u16*)src)[idx];
  }
  __syncthreads();
  u16* dst = WT + (size_t)g * H * H;
#pragma unroll
  for (int p = 0; p < 16; ++p) {
    int e = p * 256 + tid;
    int jr = e >> 6, kc = e & 63;
    dst[(size_t)(j0 + jr) * H + k0 + kc] = tile[kc][jr];
  }
}

// xproj[m, g*256+j] = ins[m,:] @ W_ig[:,j]  -> bf16
#define LDK 40
__global__ __launch_bounds__(256) void kgemm(const void* __restrict__ ins,
                                             const u16* __restrict__ insb, int use_insb,
                                             int t0, const u16* __restrict__ WT,
                                             u16* __restrict__ C,
                                             const int* __restrict__ flags) {
  __shared__ u16 As[128 * LDK];
  __shared__ u16 Bs[128 * LDK];
  bool f32in = flags[0] != 0;
  int tid = threadIdx.x;
  int row0 = blockIdx.x * 128;
  int col0 = blockIdx.y * 128;
  int gate = col0 >> 8;
  int j0 = col0 & 255;
  const u16* Bg = WT + (size_t)gate * H * H + (size_t)j0 * H;
  size_t abase = (size_t)t0 * BA * H;
  int lane = tid & 63;
  int wave = tid >> 6;
  int r16 = lane & 15;
  int kg = lane >> 4;
  f4_t acc[2][8];
#pragma unroll
  for (int rt = 0; rt < 2; ++rt)
#pragma unroll
    for (int ct = 0; ct < 8; ++ct) acc[rt][ct] = (f4_t)0.0f;

  for (int kk = 0; kk < 8; ++kk) {
    int k0 = kk * 32;
#pragma unroll
    for (int p = 0; p < 2; ++p) {
      int idx = p * 256 + tid;
      int m = idx >> 2;
      int kq = (idx & 3) * 8;
      size_t e = abase + (size_t)(row0 + m) * H + k0 + kq;
      s8_t v;
      if (use_insb) {
        v = *(const s8_t*)(insb + e);
      } else if (f32in) {
        f4_t x0 = *(const f4_t*)((const float*)ins + e);
        f4_t x1 = *(const f4_t*)((const float*)ins + e + 4);
#pragma unroll
        for (int i = 0; i < 4; ++i) v[i] = (short)f2bf(x0[i]);
#pragma unroll
        for (int i = 0; i < 4; ++i) v[4 + i] = (short)f2bf(x1[i]);
      } else {
        v = *(const s8_t*)((const u16*)ins + e);
      }
      *(s8_t*)(As + m * LDK + kq) = v;
    }
#pragma unroll
    for (int p = 0; p < 2; ++p) {
      int idx = p * 256 + tid;
      int n = idx >> 2;
      int kq = (idx & 3) * 8;
      s8_t v = *(const s8_t*)(Bg + (size_t)n * H + k0 + kq);
      *(s8_t*)(Bs + n * LDK + kq) = v;
    }
    __syncthreads();
    s8_t af[2], bf[8];
#pragma unroll
    for (int rt = 0; rt < 2; ++rt)
      af[rt] = *(const s8_t*)(As + (wave * 32 + rt * 16 + r16) * LDK + kg * 8);
#pragma unroll
    for (int ct = 0; ct < 8; ++ct)
      bf[ct] = *(const s8_t*)(Bs + (ct * 16 + r16) * LDK + kg * 8);
#pragma unroll
    for (int rt = 0; rt < 2; ++rt)
#pragma unroll
      for (int ct = 0; ct < 8; ++ct)
        acc[rt][ct] = __builtin_amdgcn_mfma_f32_16x16x32_bf16(af[rt], bf[ct], acc[rt][ct], 0, 0, 0);
    __syncthreads();
  }
#pragma unroll
  for (int rt = 0; rt < 2; ++rt)
#pragma unroll
    for (int ct = 0; ct < 8; ++ct)
#pragma unroll
      for (int r = 0; r < 4; ++r) {
        int grow = row0 + wave * 32 + rt * 16 + kg * 4 + r;
        int gcol = col0 + ct * 16 + r16;
        C[(size_t)grow * TH + gcol] = f2bf(acc[rt][ct][r]);
      }
}

// -------- macro-expanded weight pack (literal vector indices => pure insertelement) ---
#define PKC(VR, P, c) { s8_t b_ = *(const s8_t*)((P) + (c) * 8); \
  VR[(c)*4+0] = pk(b_[0], b_[1]); VR[(c)*4+1] = pk(b_[2], b_[3]); \
  VR[(c)*4+2] = pk(b_[4], b_[5]); VR[(c)*4+3] = pk(b_[6], b_[7]); }
#define PKROW(VR, P) \
  PKC(VR,P,0) PKC(VR,P,1) PKC(VR,P,2) PKC(VR,P,3) PKC(VR,P,4) PKC(VR,P,5) PKC(VR,P,6) PKC(VR,P,7) \
  PKC(VR,P,8) PKC(VR,P,9) PKC(VR,P,10) PKC(VR,P,11) PKC(VR,P,12) PKC(VR,P,13) PKC(VR,P,14) PKC(VR,P,15) \
  PKC(VR,P,16) PKC(VR,P,17) PKC(VR,P,18) PKC(VR,P,19) PKC(VR,P,20) PKC(VR,P,21) PKC(VR,P,22) PKC(VR,P,23) \
  PKC(VR,P,24) PKC(VR,P,25) PKC(VR,P,26) PKC(VR,P,27) PKC(VR,P,28) PKC(VR,P,29) PKC(VR,P,30) PKC(VR,P,31)

#define BCH(x) __builtin_bit_cast(h2_t, (u32)(x))
#define DOTQ(q) { uint4 hv_ = h4_[q]; \
  h2_t a0_ = __builtin_bit_cast(h2_t, hv_.x); \
  h2_t a1_ = __builtin_bit_cast(h2_t, hv_.y); \
  h2_t a2_ = __builtin_bit_cast(h2_t, hv_.z); \
  h2_t a3_ = __builtin_bit_cast(h2_t, hv_.w); \
  ar = F2(BCH(WR[4*(q)+0]), a0_, ar); az = F2(BCH(WZ[4*(q)+0]), a0_, az); an = F2(BCH(WN[4*(q)+0]), a0_, an); \
  ar = F2(BCH(WR[4*(q)+1]), a1_, ar); az = F2(BCH(WZ[4*(q)+1]), a1_, az); an = F2(BCH(WN[4*(q)+1]), a1_, an); \
  ar = F2(BCH(WR[4*(q)+2]), a2_, ar); az = F2(BCH(WZ[4*(q)+2]), a2_, az); an = F2(BCH(WN[4*(q)+2]), a2_, an); \
  ar = F2(BCH(WR[4*(q)+3]), a3_, ar); az = F2(BCH(WZ[4*(q)+3]), a3_, az); an = F2(BCH(WN[4*(q)+3]), a3_, an); }
#define DOT32 \
  DOTQ(0) DOTQ(1) DOTQ(2) DOTQ(3) DOTQ(4) DOTQ(5) DOTQ(6) DOTQ(7) \
  DOTQ(8) DOTQ(9) DOTQ(10) DOTQ(11) DOTQ(12) DOTQ(13) DOTQ(14) DOTQ(15) \
  DOTQ(16) DOTQ(17) DOTQ(18) DOTQ(19) DOTQ(20) DOTQ(21) DOTQ(22) DOTQ(23) \
  DOTQ(24) DOTQ(25) DOTQ(26) DOTQ(27) DOTQ(28) DOTQ(29) DOTQ(30) DOTQ(31)

// GRU scan: one WG per (b,a) sequence; weights register-resident as named ext-vectors
__global__ __launch_bounds__(256, 1) void kscan(
    const u16* __restrict__ xproj, const void* __restrict__ resets,
    const void* __restrict__ h0, float* __restrict__ carry,
    const u16* __restrict__ WhT,  // [3][256][256], row j contiguous in k
    const void* __restrict__ bir, const void* __restrict__ biz, const void* __restrict__ bin_,
    const void* __restrict__ bhn, float* __restrict__ out, int t0, int Tc,
    const int* __restrict__ flags) {
  int w = blockIdx.x;
  int j = threadIdx.x;
  bool wf32 = flags[2] != 0;
  bool rbyte = flags[1] != 0;
  __shared__ __align__(16) u32 hs[256];  // double-buffered f16 h (2 x 128 pairs)
  __shared__ int rstS[1024];

  for (int t = j; t < Tc; t += 256)
    rstS[t] = ldrst(resets, rbyte, (size_t)(t0 + t) * BA + w);

  const u16* pr = WhT + (size_t)j * H;
  const u16* pz = WhT + (size_t)H * H + (size_t)j * H;
  const u16* pn = WhT + (size_t)2 * H * H + (size_t)j * H;
  v128u WR, WZ, WN;
  PKROW(WR, pr)
  PKROW(WZ, pz)
  PKROW(WN, pn)

  float vbir = ldf(bir, wf32, j), vbiz = ldf(biz, wf32, j);
  float vbin = ldf(bin_, wf32, j), vbhn = ldf(bhn, wf32, j);

  float hreg = (t0 == 0) ? ldf(h0, wf32, (size_t)w * H + j) : carry[(size_t)w * H + j];
  __syncthreads();  // rstS visible
  if (rstS[0] != 0) hreg = 0.0f;
  ((_Float16*)hs)[j] = (_Float16)hreg;  // buffer 0
  __syncthreads();

  size_t xb0 = (size_t)w * TH + j;
  u16 cxr = xproj[xb0], cxz = xproj[xb0 + H], cxn = xproj[xb0 + 2 * H];

#pragma unroll 1
  for (int tl = 0; tl < Tc; ++tl) {
    u16 nxr = 0, nxz = 0, nxn = 0;
    if (tl + 1 < Tc) {  // prefetch next step's xproj
      size_t nb = ((size_t)(tl + 1) * BA + w) * TH + j;
      nxr = xproj[nb]; nxz = xproj[nb + H]; nxn = xproj[nb + 2 * H];
    }
    const uint4* h4_ = (const uint4*)(hs + ((tl & 1) ? 128 : 0));
    float ar = 0.0f, az = 0.0f, an = 0.0f;
    DOT32
    float r = sigm(bf2f(cxr) + vbir + ar);
    float z = sigm(bf2f(cxz) + vbiz + az);
    float n = tanh_(bf2f(cxn) + vbin + r * (an + vbhn));
    float hnew = (1.0f - z) * n + z * hreg;
    out[((size_t)(t0 + tl) * BA + w) * H + j] = hnew;

    float hnext = hnew;
    if (tl + 1 < Tc && rstS[tl + 1] != 0) hnext = 0.0f;
    ((_Float16*)(hs + ((tl & 1) ? 0 : 128)))[j] = (_Float16)hnext;  // write other buffer
    hreg = hnext;
    cxr = nxr; cxz = nxz; cxn = nxn;
    __syncthreads();  // single barrier: writes visible, all reads of old buffer done
  }
  carry[(size_t)w * H + j] = hreg;
}

extern "C" void kernel_launch(void* const* d_in, const int* in_sizes, int n_in,
                              void* d_out, int out_size, void* d_ws, size_t ws_size,
                              hipStream_t stream) {
  const void* ins = d_in[0];
  const void* resets = d_in[1];
  const void* h0 = d_in[2];
  const void* Wir = d_in[3];
  const void* Wiz = d_in[4];
  const void* Win = d_in[5];
  const void* bir = d_in[6];
  const void* biz = d_in[7];
  const void* bin_ = d_in[8];
  const void* Whr = d_in[9];
  const void* Whz = d_in[10];
  const void* Whn = d_in[11];
  const void* bhn = d_in[12];
  float* out = (float*)d_out;

  // ws: [flags 256B][WT6 768KB][carry 128KB][insb 64MB?][xproj Tc*192KB bf16]
  const size_t off_wt = 256;
  const size_t wt_bytes = (size_t)6 * H * H * 2;      // 786432
  const size_t off_carry = off_wt + wt_bytes;
  const size_t off_insb = off_carry + (size_t)BA * H * 4;
  const size_t insb_bytes = (size_t)1024 * BA * H * 2;  // 64 MB
  const size_t chunk_bytes = (size_t)BA * TH * 2;       // 192 KB per t
  int use_insb = (ws_size >= off_insb + insb_bytes + chunk_bytes) ? 1 : 0;
  size_t off_xproj = use_insb ? (off_insb + insb_bytes) : off_insb;

  int Tc = 1024;
  while (Tc > 1 && off_xproj + (size_t)Tc * chunk_bytes > ws_size) Tc >>= 1;

  int* flags = (int*)d_ws;
  u16* WT = (u16*)((char*)d_ws + off_wt);
  float* carry = (float*)((char*)d_ws + off_carry);
  u16* insb = (u16*)((char*)d_ws + off_insb);
  u16* xproj = (u16*)((char*)d_ws + off_xproj);

  kdetect<<<1, 256, 0, stream>>>((const u32*)ins, (const u32*)resets,
                                 (const u32*)Whr, (const u32*)Wir, flags);
  if (use_insb) kprep<<<16384, 256, 0, stream>>>(ins, insb, flags);
  ktrans<<<dim3(4, 4, 6), 256, 0, stream>>>(Wir, Wiz, Win, Whr, Whz, Whn, WT, flags);
  int nchunks = 1024 / Tc;
  for (int c = 0; c < nchunks; ++c) {
    int t0 = c * Tc;
    kgemm<<<dim3(Tc, 6), 256, 0, stream>>>(ins, insb, use_insb, t0, WT, xproj + (size_t)0, flags);
    kscan<<<128, 256, 0, stream>>>(xproj, resets, h0, carry, WT + (size_t)3 * H * H,
                                   bir, biz, bin_, bhn, out, t0, Tc, flags);
  }
}

// Round 5
// 1518.687 us; speedup vs baseline: 2.3534x; 1.8947x over previous
//
#include <hip/hip_runtime.h>

#define BA 128
#define H 256
#define TH 768

typedef _Float16 h2_t __attribute__((ext_vector_type(2)));
typedef short s8_t __attribute__((ext_vector_type(8)));
typedef float f4_t __attribute__((ext_vector_type(4)));
typedef unsigned short u16;
typedef unsigned int u32;
typedef u32 v64u __attribute__((ext_vector_type(64)));

__device__ __forceinline__ float bf2f(u16 u) {
  union { u32 i; float f; } c; c.i = ((u32)u) << 16; return c.f;
}
__device__ __forceinline__ u16 f2bf(float f) {
  union { float f; u32 i; } c; c.f = f;
  u32 r = c.i + 0x7FFFu + ((c.i >> 16) & 1u);
  return (u16)(r >> 16);
}
__device__ __forceinline__ float sigm(float x) {
  float e = __builtin_amdgcn_exp2f(-x * 1.442695040888963f);
  return __builtin_amdgcn_rcpf(1.0f + e);
}
__device__ __forceinline__ float tanh_(float x) {
  float e = __builtin_amdgcn_exp2f(x * 2.885390081777927f);
  return 1.0f - 2.0f * __builtin_amdgcn_rcpf(1.0f + e);
}
__device__ __forceinline__ float ldf(const void* p, bool f32, size_t idx) {
  return f32 ? ((const float*)p)[idx] : bf2f(((const u16*)p)[idx]);
}
__device__ __forceinline__ int ldrst(const void* p, bool isbyte, size_t idx) {
  return isbyte ? (int)((const unsigned char*)p)[idx] : ((const int*)p)[idx];
}
__device__ __forceinline__ float F2(h2_t a, h2_t b, float c) {
#if defined(__has_builtin) && __has_builtin(__builtin_amdgcn_fdot2)
  return __builtin_amdgcn_fdot2(a, b, c, false);
#else
  return c + (float)a[0] * (float)b[0] + (float)a[1] * (float)b[1];
#endif
}

// flags: [0]=ins_f32 [1]=resets_byte [2]=Wh_f32 [3]=Wi_f32
__global__ __launch_bounds__(256) void kdetect(const u32* __restrict__ insw,
                                               const u32* __restrict__ rstw,
                                               const u32* __restrict__ whrw,
                                               const u32* __restrict__ wirw,
                                               int* __restrict__ flags) {
  __shared__ int c0, c1, c2, c3;
  if (threadIdx.x == 0) { c0 = 0; c1 = 0; c2 = 0; c3 = 0; }
  __syncthreads();
  if (!(fabsf(bf2f((u16)(insw[threadIdx.x] & 0xFFFFu))) < 1e10f)) atomicAdd(&c0, 1);
  if (!(fabsf(bf2f((u16)(whrw[threadIdx.x] & 0xFFFFu))) < 1e10f)) atomicAdd(&c2, 1);
  if (!(fabsf(bf2f((u16)(wirw[threadIdx.x] & 0xFFFFu))) < 1e10f)) atomicAdd(&c3, 1);
  if (threadIdx.x < 128 && rstw[threadIdx.x] > 1u) atomicAdd(&c1, 1);
  __syncthreads();
  if (threadIdx.x == 0) {
    flags[0] = (c0 > 8) ? 1 : 0;
    flags[1] = (c1 > 0) ? 1 : 0;
    flags[2] = (c2 > 8) ? 1 : 0;
    flags[3] = (c3 > 8) ? 1 : 0;
  }
}

// convert ins -> bf16 (or pass-through)
__global__ __launch_bounds__(256) void kprep(const void* __restrict__ ins,
                                             u16* __restrict__ insb,
                                             const int* __restrict__ flags) {
  bool f32in = flags[0] != 0;
  size_t i0 = ((size_t)blockIdx.x * 256 + threadIdx.x) * 8;
  s8_t v;
  if (f32in) {
    f4_t x0 = *(const f4_t*)((const float*)ins + i0);
    f4_t x1 = *(const f4_t*)((const float*)ins + i0 + 4);
#pragma unroll
    for (int i = 0; i < 4; ++i) v[i] = (short)f2bf(x0[i]);
#pragma unroll
    for (int i = 0; i < 4; ++i) v[4 + i] = (short)f2bf(x1[i]);
  } else {
    v = *(const s8_t*)((const u16*)ins + i0);
  }
  *(s8_t*)(insb + i0) = v;
}

// WT[g][j][k] = W_g[k][j]; g=0..2 (Wi): bf16 for MFMA; g=3..5 (Wh): f16 for the scan
__global__ __launch_bounds__(256) void ktrans(const void* __restrict__ W0, const void* __restrict__ W1,
                                              const void* __restrict__ W2, const void* __restrict__ W3,
                                              const void* __restrict__ W4, const void* __restrict__ W5,
                                              u16* __restrict__ WT, const int* __restrict__ flags) {
  __shared__ u16 tile[64][65];
  int g = blockIdx.z;
  bool f32in = ((g < 3) ? flags[3] : flags[2]) != 0;
  bool toF16 = (g >= 3);
  const void* srcs[6] = {W0, W1, W2, W3, W4, W5};
  const void* src = srcs[g];
  int k0 = blockIdx.x * 64, j0 = blockIdx.y * 64;
  int tid = threadIdx.x;
#pragma unroll
  for (int p = 0; p < 16; ++p) {
    int e = p * 256 + tid;
    int kr = e >> 6, jc = e & 63;
    size_t idx = (size_t)(k0 + kr) * H + j0 + jc;
    float v = f32in ? ((const float*)src)[idx] : bf2f(((const u16*)src)[idx]);
    u16 bits;
    if (toF16) {
      _Float16 h = (_Float16)v;
      bits = __builtin_bit_cast(u16, h);
    } else {
      bits = f2bf(v);
    }
    tile[kr][jc] = bits;
  }
  __syncthreads();
  u16* dst = WT + (size_t)g * H * H;
#pragma unroll
  for (int p = 0; p < 16; ++p) {
    int e = p * 256 + tid;
    int jr = e >> 6, kc = e & 63;
    dst[(size_t)(j0 + jr) * H + k0 + kc] = tile[kc][jr];
  }
}

// xproj[m, g*256+j] = ins[m,:] @ W_ig[:,j]  -> bf16
#define LDK 40
__global__ __launch_bounds__(256) void kgemm(const void* __restrict__ ins,
                                             const u16* __restrict__ insb, int use_insb,
                                             int t0, const u16* __restrict__ WT,
                                             u16* __restrict__ C,
                                             const int* __restrict__ flags) {
  __shared__ u16 As[128 * LDK];
  __shared__ u16 Bs[128 * LDK];
  bool f32in = flags[0] != 0;
  int tid = threadIdx.x;
  int row0 = blockIdx.x * 128;
  int col0 = blockIdx.y * 128;
  int gate = col0 >> 8;
  int j0 = col0 & 255;
  const u16* Bg = WT + (size_t)gate * H * H + (size_t)j0 * H;
  size_t abase = (size_t)t0 * BA * H;
  int lane = tid & 63;
  int wave = tid >> 6;
  int r16 = lane & 15;
  int kg = lane >> 4;
  f4_t acc[2][8];
#pragma unroll
  for (int rt = 0; rt < 2; ++rt)
#pragma unroll
    for (int ct = 0; ct < 8; ++ct) acc[rt][ct] = (f4_t)0.0f;

  for (int kk = 0; kk < 8; ++kk) {
    int k0 = kk * 32;
#pragma unroll
    for (int p = 0; p < 2; ++p) {
      int idx = p * 256 + tid;
      int m = idx >> 2;
      int kq = (idx & 3) * 8;
      size_t e = abase + (size_t)(row0 + m) * H + k0 + kq;
      s8_t v;
      if (use_insb) {
        v = *(const s8_t*)(insb + e);
      } else if (f32in) {
        f4_t x0 = *(const f4_t*)((const float*)ins + e);
        f4_t x1 = *(const f4_t*)((const float*)ins + e + 4);
#pragma unroll
        for (int i = 0; i < 4; ++i) v[i] = (short)f2bf(x0[i]);
#pragma unroll
        for (int i = 0; i < 4; ++i) v[4 + i] = (short)f2bf(x1[i]);
      } else {
        v = *(const s8_t*)((const u16*)ins + e);
      }
      *(s8_t*)(As + m * LDK + kq) = v;
    }
#pragma unroll
    for (int p = 0; p < 2; ++p) {
      int idx = p * 256 + tid;
      int n = idx >> 2;
      int kq = (idx & 3) * 8;
      s8_t v = *(const s8_t*)(Bg + (size_t)n * H + k0 + kq);
      *(s8_t*)(Bs + n * LDK + kq) = v;
    }
    __syncthreads();
    s8_t af[2], bf[8];
#pragma unroll
    for (int rt = 0; rt < 2; ++rt)
      af[rt] = *(const s8_t*)(As + (wave * 32 + rt * 16 + r16) * LDK + kg * 8);
#pragma unroll
    for (int ct = 0; ct < 8; ++ct)
      bf[ct] = *(const s8_t*)(Bs + (ct * 16 + r16) * LDK + kg * 8);
#pragma unroll
    for (int rt = 0; rt < 2; ++rt)
#pragma unroll
      for (int ct = 0; ct < 8; ++ct)
        acc[rt][ct] = __builtin_amdgcn_mfma_f32_16x16x32_bf16(af[rt], bf[ct], acc[rt][ct], 0, 0, 0);
    __syncthreads();
  }
#pragma unroll
  for (int rt = 0; rt < 2; ++rt)
#pragma unroll
    for (int ct = 0; ct < 8; ++ct)
#pragma unroll
      for (int r = 0; r < 4; ++r) {
        int grow = row0 + wave * 32 + rt * 16 + kg * 4 + r;
        int gcol = col0 + ct * 16 + r16;
        C[(size_t)grow * TH + gcol] = f2bf(acc[rt][ct][r]);
      }
}

// ---- scan: 512 threads = (j, k-half); 192 weight VGPRs/thread; shfl-pair reduction ----
#define LDW(VR, P, c) { uint4 q_ = *(const uint4*)((P) + (c) * 8); \
  VR[(c)*4+0] = q_.x; VR[(c)*4+1] = q_.y; VR[(c)*4+2] = q_.z; VR[(c)*4+3] = q_.w; }
#define LDWALL(VR, P) \
  LDW(VR,P,0) LDW(VR,P,1) LDW(VR,P,2) LDW(VR,P,3) LDW(VR,P,4) LDW(VR,P,5) LDW(VR,P,6) LDW(VR,P,7) \
  LDW(VR,P,8) LDW(VR,P,9) LDW(VR,P,10) LDW(VR,P,11) LDW(VR,P,12) LDW(VR,P,13) LDW(VR,P,14) LDW(VR,P,15)

#define BCH(x) __builtin_bit_cast(h2_t, (u32)(x))
#define DOTC(c) { uint4 hv_ = h4_[c]; \
  h2_t a0_ = __builtin_bit_cast(h2_t, hv_.x); \
  h2_t a1_ = __builtin_bit_cast(h2_t, hv_.y); \
  h2_t a2_ = __builtin_bit_cast(h2_t, hv_.z); \
  h2_t a3_ = __builtin_bit_cast(h2_t, hv_.w); \
  ar = F2(BCH(WR[4*(c)+0]), a0_, ar); az = F2(BCH(WZ[4*(c)+0]), a0_, az); an = F2(BCH(WN[4*(c)+0]), a0_, an); \
  ar = F2(BCH(WR[4*(c)+1]), a1_, ar); az = F2(BCH(WZ[4*(c)+1]), a1_, az); an = F2(BCH(WN[4*(c)+1]), a1_, an); \
  ar = F2(BCH(WR[4*(c)+2]), a2_, ar); az = F2(BCH(WZ[4*(c)+2]), a2_, az); an = F2(BCH(WN[4*(c)+2]), a2_, an); \
  ar = F2(BCH(WR[4*(c)+3]), a3_, ar); az = F2(BCH(WZ[4*(c)+3]), a3_, az); an = F2(BCH(WN[4*(c)+3]), a3_, an); }
#define DOT16 \
  DOTC(0) DOTC(1) DOTC(2) DOTC(3) DOTC(4) DOTC(5) DOTC(6) DOTC(7) \
  DOTC(8) DOTC(9) DOTC(10) DOTC(11) DOTC(12) DOTC(13) DOTC(14) DOTC(15)

__global__ __launch_bounds__(512, 2) void kscan(
    const u16* __restrict__ xproj, const void* __restrict__ resets,
    const void* __restrict__ h0, float* __restrict__ carry,
    const u16* __restrict__ WhF,  // [3][256][256] f16, row j contiguous in k
    const void* __restrict__ bir, const void* __restrict__ biz, const void* __restrict__ bin_,
    const void* __restrict__ bhn, float* __restrict__ out, int t0, int Tc,
    const int* __restrict__ flags) {
  int w = blockIdx.x;
  int tid = threadIdx.x;
  int j = tid >> 1;        // output column 0..255
  int half = tid & 1;      // k-half 0..1
  bool wf32 = flags[2] != 0;
  bool rbyte = flags[1] != 0;
  __shared__ __align__(16) u16 hsb[2][256];  // f16 h, double-buffered
  __shared__ int rstS[1024];

  for (int t = tid; t < Tc; t += 512)
    rstS[t] = ldrst(resets, rbyte, (size_t)(t0 + t) * BA + w);

  // 3 x 64 u32 (f16-pairs) of weights: W_g[k0+..][j], k0 = half*128
  const u16* pr = WhF + (size_t)j * H + half * 128;
  const u16* pz = WhF + (size_t)H * H + (size_t)j * H + half * 128;
  const u16* pn = WhF + (size_t)2 * H * H + (size_t)j * H + half * 128;
  v64u WR, WZ, WN;
  LDWALL(WR, pr)
  LDWALL(WZ, pz)
  LDWALL(WN, pn)

  float vbir = ldf(bir, wf32, j), vbiz = ldf(biz, wf32, j);
  float vbin = ldf(bin_, wf32, j), vbhn = ldf(bhn, wf32, j);

  float hreg = (t0 == 0) ? ldf(h0, wf32, (size_t)w * H + j) : carry[(size_t)w * H + j];
  __syncthreads();  // rstS visible
  if (rstS[0] != 0) hreg = 0.0f;
  if (half == 0) {
    _Float16 hh = (_Float16)hreg;
    hsb[0][j] = __builtin_bit_cast(u16, hh);
  }
  __syncthreads();

  size_t xb0 = (size_t)w * TH + j;
  u16 cxr = xproj[xb0], cxz = xproj[xb0 + H], cxn = xproj[xb0 + 2 * H];

#pragma unroll 1
  for (int tl = 0; tl < Tc; ++tl) {
    u16 nxr = 0, nxz = 0, nxn = 0;
    if (tl + 1 < Tc) {  // prefetch next step's xproj
      size_t nb = ((size_t)(tl + 1) * BA + w) * TH + j;
      nxr = xproj[nb]; nxz = xproj[nb + H]; nxn = xproj[nb + 2 * H];
    }
    const uint4* h4_ = (const uint4*)(&hsb[tl & 1][half * 128]);
    float ar = 0.0f, az = 0.0f, an = 0.0f;
    DOT16
    // combine k-halves: partner lane is tid^1 (same wave)
    ar += __shfl_xor(ar, 1, 64);
    az += __shfl_xor(az, 1, 64);
    an += __shfl_xor(an, 1, 64);
    float r = sigm(bf2f(cxr) + vbir + ar);
    float z = sigm(bf2f(cxz) + vbiz + az);
    float n = tanh_(bf2f(cxn) + vbin + r * (an + vbhn));
    float hnew = (1.0f - z) * n + z * hreg;
    if (half == 0) out[((size_t)(t0 + tl) * BA + w) * H + j] = hnew;

    float hnext = hnew;
    if (tl + 1 < Tc && rstS[tl + 1] != 0) hnext = 0.0f;
    if (half == 0) {
      _Float16 hh = (_Float16)hnext;
      hsb[(tl & 1) ^ 1][j] = __builtin_bit_cast(u16, hh);
    }
    hreg = hnext;
    cxr = nxr; cxz = nxz; cxn = nxn;
    __syncthreads();  // writes to other buffer visible; reads of current done
  }
  if (half == 0) carry[(size_t)w * H + j] = hreg;
}

extern "C" void kernel_launch(void* const* d_in, const int* in_sizes, int n_in,
                              void* d_out, int out_size, void* d_ws, size_t ws_size,
                              hipStream_t stream) {
  const void* ins = d_in[0];
  const void* resets = d_in[1];
  const void* h0 = d_in[2];
  const void* Wir = d_in[3];
  const void* Wiz = d_in[4];
  const void* Win = d_in[5];
  const void* bir = d_in[6];
  const void* biz = d_in[7];
  const void* bin_ = d_in[8];
  const void* Whr = d_in[9];
  const void* Whz = d_in[10];
  const void* Whn = d_in[11];
  const void* bhn = d_in[12];
  float* out = (float*)d_out;

  // ws: [flags 256B][WT6 768KB (Wi bf16 | Wh f16)][carry 128KB][insb 64MB?][xproj bf16]
  const size_t off_wt = 256;
  const size_t wt_bytes = (size_t)6 * H * H * 2;
  const size_t off_carry = off_wt + wt_bytes;
  const size_t off_insb = off_carry + (size_t)BA * H * 4;
  const size_t insb_bytes = (size_t)1024 * BA * H * 2;  // 64 MB
  const size_t chunk_bytes = (size_t)BA * TH * 2;       // 192 KB per t
  int use_insb = (ws_size >= off_insb + insb_bytes + chunk_bytes) ? 1 : 0;
  size_t off_xproj = use_insb ? (off_insb + insb_bytes) : off_insb;

  int Tc = 1024;
  while (Tc > 1 && off_xproj + (size_t)Tc * chunk_bytes > ws_size) Tc >>= 1;

  int* flags = (int*)d_ws;
  u16* WT = (u16*)((char*)d_ws + off_wt);
  float* carry = (float*)((char*)d_ws + off_carry);
  u16* insb = (u16*)((char*)d_ws + off_insb);
  u16* xproj = (u16*)((char*)d_ws + off_xproj);

  kdetect<<<1, 256, 0, stream>>>((const u32*)ins, (const u32*)resets,
                                 (const u32*)Whr, (const u32*)Wir, flags);
  if (use_insb) kprep<<<16384, 256, 0, stream>>>(ins, insb, flags);
  ktrans<<<dim3(4, 4, 6), 256, 0, stream>>>(Wir, Wiz, Win, Whr, Whz, Whn, WT, flags);
  int nchunks = 1024 / Tc;
  for (int c = 0; c < nchunks; ++c) {
    int t0 = c * Tc;
    kgemm<<<dim3(Tc, 6), 256, 0, stream>>>(ins, insb, use_insb, t0, WT, xproj, flags);
    kscan<<<128, 512, 0, stream>>>(xproj, resets, h0, carry, WT + (size_t)3 * H * H,
                                   bir, biz, bin_, bhn, out, t0, Tc, flags);
  }
}